// Round 7
// baseline (137.255 us; speedup 1.0000x reference)
//
#include <hip/hip_runtime.h>

#define Nn 768
#define Dd 128
#define LDP 136   // padded bf16 row stride (272 B)

typedef __attribute__((ext_vector_type(8))) short bf16x8;
typedef __attribute__((ext_vector_type(4))) float f32x4;
typedef __attribute__((ext_vector_type(4))) int   i32x4;

static __device__ __forceinline__ unsigned short f2bf(float f) {
  unsigned int u = __builtin_bit_cast(unsigned int, f);
  u += 0x7fffu + ((u >> 16) & 1u);   // RNE
  return (unsigned short)(u >> 16);
}
static __device__ __forceinline__ float bf2f(unsigned short h) {
  unsigned int u = ((unsigned int)h) << 16;
  return __builtin_bit_cast(float, u);
}
// packed f32 pair -> [bf16(hi):bf16(lo)] in one VALU op (RNE)
static __device__ __forceinline__ unsigned int cvtpk(float lo, float hi) {
  unsigned int r;
  asm("v_cvt_pk_bf16_f32 %0, %1, %2" : "=v"(r) : "v"(lo), "v"(hi));
  return r;
}

// left[i][e] = sum_d x[i][d] * W_in[e][d] + b_in[e], stored bf16
__global__ __launch_bounds__(128)
void k_left(const float* __restrict__ x, const float* __restrict__ Win,
            const float* __restrict__ bin, unsigned short* __restrict__ left) {
  __shared__ float sx[Dd];
  const int i = blockIdx.x;
  const int e = threadIdx.x;
  sx[e] = x[i * Dd + e];
  __syncthreads();
  const float4* wrow = (const float4*)(Win + e * Dd);
  float a0 = 0.f, a1 = 0.f, a2 = 0.f, a3 = 0.f;
#pragma unroll
  for (int d4 = 0; d4 < Dd / 4; d4 += 4) {
    float4 w0 = wrow[d4+0], w1 = wrow[d4+1], w2 = wrow[d4+2], w3 = wrow[d4+3];
    a0 += sx[4*d4+ 0]*w0.x + sx[4*d4+ 1]*w0.y + sx[4*d4+ 2]*w0.z + sx[4*d4+ 3]*w0.w;
    a1 += sx[4*d4+ 4]*w1.x + sx[4*d4+ 5]*w1.y + sx[4*d4+ 6]*w1.z + sx[4*d4+ 7]*w1.w;
    a2 += sx[4*d4+ 8]*w2.x + sx[4*d4+ 9]*w2.y + sx[4*d4+10]*w2.z + sx[4*d4+11]*w2.w;
    a3 += sx[4*d4+12]*w3.x + sx[4*d4+13]*w3.y + sx[4*d4+14]*w3.z + sx[4*d4+15]*w3.w;
  }
  left[i * Dd + e] = f2bf(((a0 + a1) + (a2 + a3)) + bin[e]);
}

// out[i, j, e] = sum_d left[j][d] * (W_out[e][d]*left[i][d]) + b_out[e]
// One block per (i, j-half). sB staged ONCE (2 barriers total), then 3
// barrier-free j-tiles: A-frags from global left (L2-hot), MFMA, plain stores.
__global__ __launch_bounds__(256, 3)
void k_outer(const unsigned short* __restrict__ left, const float* __restrict__ Wout,
             const float* __restrict__ bout, float* __restrict__ out) {
  __shared__ __attribute__((aligned(16))) unsigned short sB[128 * LDP]; // Wout[e][d]*l_i[d]
  __shared__ float sLi[Dd];
  __shared__ float sBo[Dd];

  const int bid = blockIdx.x;   // 0..1535
  const int i   = bid >> 1;     // 0..767
  const int jh  = bid & 1;      // j-tiles jh*3 .. jh*3+2
  const int t   = threadIdx.x;  // 0..255

  if (t < Dd) {
    sLi[t] = bf2f(left[i * Dd + t]);
    sBo[t] = bout[t];
  }
  __syncthreads();

  // Stage sB: thread covers col-chunk c8 (fixed) x 8 rows; sLi hoisted to regs.
  {
    const int row = t >> 4;          // 0..15
    const int c8  = (t & 15) * 8;
    float l[8];
#pragma unroll
    for (int q = 0; q < 8; ++q) l[q] = sLi[c8 + q];
#pragma unroll
    for (int it = 0; it < 8; ++it) {
      const int r = row + it * 16;   // 0..127
      const float4* wp = (const float4*)(Wout + r * Dd + c8);
      float4 w0 = wp[0], w1 = wp[1];
      i32x4 vb;
      vb[0] = (int)cvtpk(w0.x * l[0], w0.y * l[1]);
      vb[1] = (int)cvtpk(w0.z * l[2], w0.w * l[3]);
      vb[2] = (int)cvtpk(w1.x * l[4], w1.y * l[5]);
      vb[3] = (int)cvtpk(w1.z * l[6], w1.w * l[7]);
      *(i32x4*)(sB + r * LDP + c8) = vb;
    }
  }
  __syncthreads();

  const int wid  = t >> 6;        // wave 0..3 -> j rows [wid*32, wid*32+32)
  const int lane = t & 63;
  const int l15  = lane & 15;
  const int kq   = (lane >> 4) * 8;

  float bias[8];
#pragma unroll
  for (int n = 0; n < 8; ++n) bias[n] = sBo[n * 16 + l15];

#pragma unroll 1
  for (int jj = 0; jj < 3; ++jj) {
    const int jt = jh * 3 + jj;

    const unsigned short* gA = left + (size_t)(jt * 128 + wid * 32 + l15) * Dd;

    f32x4 acc[2][8] = {};   // [j-frag][e-chunk]
#pragma unroll
    for (int kb = 0; kb < 4; ++kb) {
      const int k = kb * 32 + kq;
      bf16x8 a0 = *(const bf16x8*)(gA + k);
      bf16x8 a1 = *(const bf16x8*)(gA + 16 * Dd + k);
#pragma unroll
      for (int n = 0; n < 8; ++n) {
        bf16x8 b = *(const bf16x8*)(sB + (n * 16 + l15) * LDP + k);
        acc[0][n] = __builtin_amdgcn_mfma_f32_16x16x32_bf16(a0, b, acc[0][n], 0, 0, 0);
        acc[1][n] = __builtin_amdgcn_mfma_f32_16x16x32_bf16(a1, b, acc[1][n], 0, 0, 0);
      }
    }

    // R1-proven epilogue: row(j) = (lane>>4)*4 + r, col(e) = n*16 + l15.
#pragma unroll
    for (int jb = 0; jb < 2; ++jb) {
#pragma unroll
      for (int r = 0; r < 4; ++r) {
        const int j = jt * 128 + wid * 32 + jb * 16 + (lane >> 4) * 4 + r;
        float* orow = out + ((size_t)i * Nn + j) * Dd;
#pragma unroll
        for (int n = 0; n < 8; ++n) {
          orow[n * 16 + l15] = acc[jb][n][r] + bias[n];
        }
      }
    }
  }
}

extern "C" void kernel_launch(void* const* d_in, const int* in_sizes, int n_in,
                              void* d_out, int out_size, void* d_ws, size_t ws_size,
                              hipStream_t stream) {
  const float* x    = (const float*)d_in[0];
  const float* Win  = (const float*)d_in[1];
  const float* bin  = (const float*)d_in[2];
  const float* Wout = (const float*)d_in[3];
  const float* bout = (const float*)d_in[4];
  float* out = (float*)d_out;
  unsigned short* left = (unsigned short*)d_ws;  // 768*128 bf16 = 192 KiB

  k_left<<<Nn, Dd, 0, stream>>>(x, Win, bin, left);
  k_outer<<<Nn * 2, 256, 0, stream>>>(left, Wout, bout, out);
}

// Round 8
// 70.891 us; speedup vs baseline: 1.9361x; 1.9361x over previous
//
#include <hip/hip_runtime.h>

#define Nn 768
#define Dd 128
#define LDP 136   // padded bf16 row stride (272 B)

typedef __attribute__((ext_vector_type(8))) short bf16x8;
typedef __attribute__((ext_vector_type(4))) float f32x4;
typedef __attribute__((ext_vector_type(4))) int   i32x4;

static __device__ __forceinline__ unsigned short f2bf(float f) {
  unsigned int u = __builtin_bit_cast(unsigned int, f);
  u += 0x7fffu + ((u >> 16) & 1u);   // RNE
  return (unsigned short)(u >> 16);
}
static __device__ __forceinline__ float bf2f(unsigned short h) {
  unsigned int u = ((unsigned int)h) << 16;
  return __builtin_bit_cast(float, u);
}
// packed f32 pair -> [bf16(hi):bf16(lo)] in one VALU op (RNE)
static __device__ __forceinline__ unsigned int cvtpk(float lo, float hi) {
  unsigned int r;
  asm("v_cvt_pk_bf16_f32 %0, %1, %2" : "=v"(r) : "v"(lo), "v"(hi));
  return r;
}

// left[i][e] = sum_d x[i][d] * W_in[e][d] + b_in[e], stored bf16
__global__ __launch_bounds__(128)
void k_left(const float* __restrict__ x, const float* __restrict__ Win,
            const float* __restrict__ bin, unsigned short* __restrict__ left) {
  __shared__ float sx[Dd];
  const int i = blockIdx.x;
  const int e = threadIdx.x;
  sx[e] = x[i * Dd + e];
  __syncthreads();
  const float4* wrow = (const float4*)(Win + e * Dd);
  float a0 = 0.f, a1 = 0.f, a2 = 0.f, a3 = 0.f;
#pragma unroll
  for (int d4 = 0; d4 < Dd / 4; d4 += 4) {
    float4 w0 = wrow[d4+0], w1 = wrow[d4+1], w2 = wrow[d4+2], w3 = wrow[d4+3];
    a0 += sx[4*d4+ 0]*w0.x + sx[4*d4+ 1]*w0.y + sx[4*d4+ 2]*w0.z + sx[4*d4+ 3]*w0.w;
    a1 += sx[4*d4+ 4]*w1.x + sx[4*d4+ 5]*w1.y + sx[4*d4+ 6]*w1.z + sx[4*d4+ 7]*w1.w;
    a2 += sx[4*d4+ 8]*w2.x + sx[4*d4+ 9]*w2.y + sx[4*d4+10]*w2.z + sx[4*d4+11]*w2.w;
    a3 += sx[4*d4+12]*w3.x + sx[4*d4+13]*w3.y + sx[4*d4+14]*w3.z + sx[4*d4+15]*w3.w;
  }
  left[i * Dd + e] = f2bf(((a0 + a1) + (a2 + a3)) + bin[e]);
}

// out[i, j, e] = sum_d left[j][d] * (W_out[e][d]*left[i][d]) + b_out[e]
// One block per (i, j-pair). sB staged once; BOTH tiles' A-fragments are
// preloaded into registers and fenced (s_waitcnt vmcnt(0)) BEFORE any store,
// so tile0's stores stay in flight under tile1's pure reg+LDS MFMA.
__global__ __launch_bounds__(256, 3)
void k_outer(const unsigned short* __restrict__ left, const float* __restrict__ Wout,
             const float* __restrict__ bout, float* __restrict__ out) {
  __shared__ __attribute__((aligned(16))) unsigned short sB[128 * LDP]; // Wout[e][d]*l_i[d]
  __shared__ float sLi[Dd];
  __shared__ float sBo[Dd];

  const int bid = blockIdx.x;   // 0..2303
  const int i   = bid / 3;      // 0..767  (3 consecutive blocks share i)
  const int jh  = bid % 3;      // j-tiles jh*2, jh*2+1
  const int t   = threadIdx.x;  // 0..255

  if (t < Dd) {
    sLi[t] = bf2f(left[i * Dd + t]);
    sBo[t] = bout[t];
  }
  __syncthreads();

  // Stage sB (cvt_pk packing, sLi hoisted to regs).
  {
    const int row = t >> 4;          // 0..15
    const int c8  = (t & 15) * 8;
    float l[8];
#pragma unroll
    for (int q = 0; q < 8; ++q) l[q] = sLi[c8 + q];
#pragma unroll
    for (int it = 0; it < 8; ++it) {
      const int r = row + it * 16;   // 0..127
      const float4* wp = (const float4*)(Wout + r * Dd + c8);
      float4 w0 = wp[0], w1 = wp[1];
      i32x4 vb;
      vb[0] = (int)cvtpk(w0.x * l[0], w0.y * l[1]);
      vb[1] = (int)cvtpk(w0.z * l[2], w0.w * l[3]);
      vb[2] = (int)cvtpk(w1.x * l[4], w1.y * l[5]);
      vb[3] = (int)cvtpk(w1.z * l[6], w1.w * l[7]);
      *(i32x4*)(sB + r * LDP + c8) = vb;
    }
  }
  __syncthreads();

  const int wid  = t >> 6;        // wave 0..3 -> j rows [wid*32, wid*32+32)
  const int lane = t & 63;
  const int l15  = lane & 15;
  const int kq   = (lane >> 4) * 8;

  float bias[8];
#pragma unroll
  for (int n = 0; n < 8; ++n) bias[n] = sBo[n * 16 + l15];

  // Preload BOTH tiles' A-fragments (left is L2/L3-hot, 192 KB).
  bf16x8 A[2][2][4];   // [tile][j-half][kb]
#pragma unroll
  for (int tt = 0; tt < 2; ++tt) {
    const unsigned short* gA = left + (size_t)((jh * 2 + tt) * 128 + wid * 32 + l15) * Dd;
#pragma unroll
    for (int kb = 0; kb < 4; ++kb) {
      A[tt][0][kb] = *(const bf16x8*)(gA + kb * 32 + kq);
      A[tt][1][kb] = *(const bf16x8*)(gA + 16 * Dd + kb * 32 + kq);
    }
  }
  // Fence: all A-loads complete here; nothing after this waits on vmcnt,
  // so the store streams below are pure issue-and-forget.
  asm volatile("s_waitcnt vmcnt(0)" ::: "memory");

#pragma unroll
  for (int tt = 0; tt < 2; ++tt) {
    const int jt = jh * 2 + tt;

    f32x4 acc[2][8] = {};   // [j-frag][e-chunk]
#pragma unroll
    for (int kb = 0; kb < 4; ++kb) {
      const int k = kb * 32 + kq;
#pragma unroll
      for (int n = 0; n < 8; ++n) {
        bf16x8 b = *(const bf16x8*)(sB + (n * 16 + l15) * LDP + k);
        acc[0][n] = __builtin_amdgcn_mfma_f32_16x16x32_bf16(A[tt][0][kb], b, acc[0][n], 0, 0, 0);
        acc[1][n] = __builtin_amdgcn_mfma_f32_16x16x32_bf16(A[tt][1][kb], b, acc[1][n], 0, 0, 0);
      }
    }

    // R6-proven epilogue: row(j) = (lane>>4)*4 + r, col(e) = n*16 + l15.
#pragma unroll
    for (int jb = 0; jb < 2; ++jb) {
#pragma unroll
      for (int r = 0; r < 4; ++r) {
        const int j = jt * 128 + wid * 32 + jb * 16 + (lane >> 4) * 4 + r;
        float* orow = out + ((size_t)i * Nn + j) * Dd;
#pragma unroll
        for (int n = 0; n < 8; ++n) {
          orow[n * 16 + l15] = acc[jb][n][r] + bias[n];
        }
      }
    }
  }
}

extern "C" void kernel_launch(void* const* d_in, const int* in_sizes, int n_in,
                              void* d_out, int out_size, void* d_ws, size_t ws_size,
                              hipStream_t stream) {
  const float* x    = (const float*)d_in[0];
  const float* Win  = (const float*)d_in[1];
  const float* bin  = (const float*)d_in[2];
  const float* Wout = (const float*)d_in[3];
  const float* bout = (const float*)d_in[4];
  float* out = (float*)d_out;
  unsigned short* left = (unsigned short*)d_ws;  // 768*128 bf16 = 192 KiB

  k_left<<<Nn, Dd, 0, stream>>>(x, Win, bin, left);
  k_outer<<<Nn * 3, 256, 0, stream>>>(left, Wout, bout, out);
}

// Round 9
// 62.327 us; speedup vs baseline: 2.2022x; 1.1374x over previous
//
#include <hip/hip_runtime.h>

#define Nn 768
#define Dd 128
#define LDP 136   // padded bf16 row stride (272 B)

typedef __attribute__((ext_vector_type(8))) short bf16x8;
typedef __attribute__((ext_vector_type(4))) float f32x4;
typedef __attribute__((ext_vector_type(4))) int   i32x4;

static __device__ __forceinline__ unsigned short f2bf(float f) {
  unsigned int u = __builtin_bit_cast(unsigned int, f);
  u += 0x7fffu + ((u >> 16) & 1u);   // RNE
  return (unsigned short)(u >> 16);
}
static __device__ __forceinline__ float bf2f(unsigned short h) {
  unsigned int u = ((unsigned int)h) << 16;
  return __builtin_bit_cast(float, u);
}
// packed f32 pair -> [bf16(hi):bf16(lo)] in one VALU op (RNE)
static __device__ __forceinline__ unsigned int cvtpk(float lo, float hi) {
  unsigned int r;
  asm("v_cvt_pk_bf16_f32 %0, %1, %2" : "=v"(r) : "v"(lo), "v"(hi));
  return r;
}

// left[i][e] = sum_d x[i][d] * W_in[e][d] + b_in[e], stored bf16
__global__ __launch_bounds__(128)
void k_left(const float* __restrict__ x, const float* __restrict__ Win,
            const float* __restrict__ bin, unsigned short* __restrict__ left) {
  __shared__ float sx[Dd];
  const int i = blockIdx.x;
  const int e = threadIdx.x;
  sx[e] = x[i * Dd + e];
  __syncthreads();
  const float4* wrow = (const float4*)(Win + e * Dd);
  float a0 = 0.f, a1 = 0.f, a2 = 0.f, a3 = 0.f;
#pragma unroll
  for (int d4 = 0; d4 < Dd / 4; d4 += 4) {
    float4 w0 = wrow[d4+0], w1 = wrow[d4+1], w2 = wrow[d4+2], w3 = wrow[d4+3];
    a0 += sx[4*d4+ 0]*w0.x + sx[4*d4+ 1]*w0.y + sx[4*d4+ 2]*w0.z + sx[4*d4+ 3]*w0.w;
    a1 += sx[4*d4+ 4]*w1.x + sx[4*d4+ 5]*w1.y + sx[4*d4+ 6]*w1.z + sx[4*d4+ 7]*w1.w;
    a2 += sx[4*d4+ 8]*w2.x + sx[4*d4+ 9]*w2.y + sx[4*d4+10]*w2.z + sx[4*d4+11]*w2.w;
    a3 += sx[4*d4+12]*w3.x + sx[4*d4+13]*w3.y + sx[4*d4+14]*w3.z + sx[4*d4+15]*w3.w;
  }
  left[i * Dd + e] = f2bf(((a0 + a1) + (a2 + a3)) + bin[e]);
}

// out[i, j, e] = sum_d left[j][d] * (W_out[e][d]*left[i][d]) + b_out[e]
// R6 skeleton (one block per (i, j-tile), sB staged once, plain scalar
// stores) with the MFMA loop restructured for VGPR<=128 so 4 blocks/CU
// (16 waves) fit: A preloaded once (8 frags), n-loop outer, kb inner.
__global__ __launch_bounds__(256, 4)
void k_outer(const unsigned short* __restrict__ left, const float* __restrict__ Wout,
             const float* __restrict__ bout, float* __restrict__ out) {
  __shared__ __attribute__((aligned(16))) unsigned short sB[128 * LDP]; // Wout[e][d]*l_i[d]
  __shared__ float sLi[Dd];
  __shared__ float sBo[Dd];

  const int jt = blockIdx.x;   // 0..5
  const int i  = blockIdx.y;   // 0..767
  const int t  = threadIdx.x;  // 0..255

  if (t < Dd) {
    sLi[t] = bf2f(left[i * Dd + t]);
    sBo[t] = bout[t];
  }
  __syncthreads();

  // Stage sB (cvt_pk packing, sLi hoisted to regs).
  {
    const int row = t >> 4;          // 0..15
    const int c8  = (t & 15) * 8;
    float l[8];
#pragma unroll
    for (int q = 0; q < 8; ++q) l[q] = sLi[c8 + q];
#pragma unroll
    for (int it = 0; it < 8; ++it) {
      const int r = row + it * 16;   // 0..127
      const float4* wp = (const float4*)(Wout + r * Dd + c8);
      float4 w0 = wp[0], w1 = wp[1];
      i32x4 vb;
      vb[0] = (int)cvtpk(w0.x * l[0], w0.y * l[1]);
      vb[1] = (int)cvtpk(w0.z * l[2], w0.w * l[3]);
      vb[2] = (int)cvtpk(w1.x * l[4], w1.y * l[5]);
      vb[3] = (int)cvtpk(w1.z * l[6], w1.w * l[7]);
      *(i32x4*)(sB + r * LDP + c8) = vb;
    }
  }
  __syncthreads();

  const int wid  = t >> 6;        // wave 0..3 -> j rows [wid*32, wid*32+32)
  const int lane = t & 63;
  const int l15  = lane & 15;
  const int kq   = (lane >> 4) * 8;

  float bias[8];
#pragma unroll
  for (int n = 0; n < 8; ++n) bias[n] = sBo[n * 16 + l15];

  // Preload this block's 8 A-fragments once (left is L2/L3-hot, 192 KB).
  const unsigned short* gA = left + (size_t)(jt * 128 + wid * 32 + l15) * Dd;
  bf16x8 A0[4], A1[4];
#pragma unroll
  for (int kb = 0; kb < 4; ++kb) {
    A0[kb] = *(const bf16x8*)(gA + kb * 32 + kq);
    A1[kb] = *(const bf16x8*)(gA + 16 * Dd + kb * 32 + kq);
  }

  f32x4 acc[2][8] = {};   // [j-frag][e-chunk]
#pragma unroll
  for (int n = 0; n < 8; ++n) {
    const unsigned short* sBrow = sB + (n * 16 + l15) * LDP + kq;
#pragma unroll
    for (int kb = 0; kb < 4; ++kb) {
      bf16x8 b = *(const bf16x8*)(sBrow + kb * 32);
      acc[0][n] = __builtin_amdgcn_mfma_f32_16x16x32_bf16(A0[kb], b, acc[0][n], 0, 0, 0);
      acc[1][n] = __builtin_amdgcn_mfma_f32_16x16x32_bf16(A1[kb], b, acc[1][n], 0, 0, 0);
    }
  }

  // R6-proven epilogue: row(j) = (lane>>4)*4 + r, col(e) = n*16 + l15. Plain stores.
#pragma unroll
  for (int jb = 0; jb < 2; ++jb) {
#pragma unroll
    for (int r = 0; r < 4; ++r) {
      const int j = jt * 128 + wid * 32 + jb * 16 + (lane >> 4) * 4 + r;
      float* orow = out + ((size_t)i * Nn + j) * Dd;
#pragma unroll
      for (int n = 0; n < 8; ++n) {
        orow[n * 16 + l15] = acc[jb][n][r] + bias[n];
      }
    }
  }
}

extern "C" void kernel_launch(void* const* d_in, const int* in_sizes, int n_in,
                              void* d_out, int out_size, void* d_ws, size_t ws_size,
                              hipStream_t stream) {
  const float* x    = (const float*)d_in[0];
  const float* Win  = (const float*)d_in[1];
  const float* bin  = (const float*)d_in[2];
  const float* Wout = (const float*)d_in[3];
  const float* bout = (const float*)d_in[4];
  float* out = (float*)d_out;
  unsigned short* left = (unsigned short*)d_ws;  // 768*128 bf16 = 192 KiB

  k_left<<<Nn, Dd, 0, stream>>>(x, Win, bin, left);
  dim3 grid(Nn / 128, Nn);
  k_outer<<<grid, 256, 0, stream>>>(left, Wout, bout, out);
}